// Round 5
// baseline (59.885 us; speedup 1.0000x reference)
//
#include <hip/hip_runtime.h>

// IntSoftmax_Piecewise: integer softmax with piecewise deg-2 int-exp.
// out[r*1024+j] = softmax_int/128 ; out[rows*1024] = s_out = 1/128.
// The straight-through float-softmax combine in the reference is the identity
// on si, so the float softmax is never computed.
//
// Round-5 structure:
//  - e(xv) table (2048 entries, xv in [-2047,0]) built ONCE by a tiny
//    pre-kernel into d_ws (bit-identical reference ops), then block-staged
//    into LDS with 2x dwordx4 + ds_write_b128 per thread. Removes the ~280
//    VALU ops/thread the per-block build cost (half of all VALU work).
//  - floor(x/s) via Markstein correctly-rounded FMA division:
//    r=RN(1/s); q0=RN(x*r); q=RN(fma(fma(-s,q0,x), r, q0)) == RN(x/s).
//  - output: floor(RN(e*factor)*2^-25) == floor(RN(e*(factor*2^-25)))
//    (exact pow2 scaling commutes with RN; no overflow/denormal in range),
//    saving one mul per element.
//  - xv below table range falls back to the exact direct path (wave-uniform,
//    ~never taken) => correctness never depends on the data range.

constexpr int ROW = 1024;
constexpr int WPB = 4;        // one row per wave, 4 waves per 256-thread block
constexpr int TSIZE = 2048;   // table covers xv in [-(TSIZE-1), 0]

typedef float f32x4 __attribute__((ext_vector_type(4)));

// exact reference per-element int-exp (segment scan + Horner + clip + >>15)
__device__ __forceinline__ float eval_e(float xv,
                                        const float* __restrict__ lo,
                                        const float4* __restrict__ cf) {
    int seg = 0;
#pragma unroll
    for (int j = 1; j < 16; ++j) seg += (xv >= lo[j]) ? 1 : 0;
    const float4 c = cf[seg];
    float r = __fadd_rn(__fmul_rn(c.x, xv), c.y);
    r = __fadd_rn(__fmul_rn(r, xv), c.z);
    return floorf(fmaxf(r, 0.0f) * (1.0f / 32768.0f));
}

__global__ __launch_bounds__(256) void build_etab_kernel(
    const float* __restrict__ lo_bounds,
    const float* __restrict__ coeffs,
    float* __restrict__ gtab)
{
    const int i = blockIdx.x * 256 + threadIdx.x;
    if (i >= TSIZE) return;
    float lo[16];
    float4 cf[16];
#pragma unroll
    for (int j = 0; j < 16; ++j) {
        lo[j] = lo_bounds[j];
        cf[j] = make_float4(coeffs[j*3+0], coeffs[j*3+1], coeffs[j*3+2], 0.0f);
    }
    gtab[i] = eval_e((float)(i - (TSIZE - 1)), lo, cf);
}

template <bool LOAD_TAB>
__global__ __launch_bounds__(256) void intsoftmax_kernel(
    const float* __restrict__ x,
    const float* __restrict__ s_ptr,
    const float* __restrict__ lo_bounds,
    const float* __restrict__ coeffs,
    const float* __restrict__ gtab,
    float* __restrict__ out,
    int rows)
{
    __shared__ float etab[TSIZE];
    const int tid = threadIdx.x;

    if (LOAD_TAB) {
        // stage precomputed table: 2x dwordx4 load + 2x ds_write_b128
        const f32x4* __restrict__ gt = (const f32x4*)gtab;
        f32x4* lt = (f32x4*)etab;
        lt[tid]       = gt[tid];
        lt[tid + 256] = gt[tid + 256];
    } else {
        // ws too small: build in-kernel (exact reference ops)
        float lo[16];
        float4 cf[16];
#pragma unroll
        for (int j = 0; j < 16; ++j) {
            lo[j] = lo_bounds[j];
            cf[j] = make_float4(coeffs[j*3+0], coeffs[j*3+1], coeffs[j*3+2], 0.0f);
        }
        for (int i = tid; i < TSIZE; i += 256)
            etab[i] = eval_e((float)(i - (TSIZE - 1)), lo, cf);
    }
    __syncthreads();

    if (blockIdx.x == 0 && tid == 0) {
        out[(size_t)rows * ROW] = 0.0078125f;  // second tuple output: s_out
    }

    const float s = s_ptr[0];
    const float rcp = __fdiv_rn(1.0f, s);  // RN(1/s), once

    const int wave = tid >> 6;
    const int lane = tid & 63;
    const long long row = (long long)blockIdx.x * WPB + wave;
    if (row >= rows) return;

    const float4* __restrict__ xr = (const float4*)(x + row * (long long)ROW);

    // x_int = floor(RN(x/s)) via Markstein correctly-rounded division
    float xi[16];
#pragma unroll
    for (int c4 = 0; c4 < 4; ++c4) {
        const float4 v = xr[c4 * 64 + lane];
        {
            const float q0 = __fmul_rn(v.x, rcp);
            xi[c4*4+0] = floorf(__builtin_fmaf(__builtin_fmaf(-s, q0, v.x), rcp, q0));
        }
        {
            const float q0 = __fmul_rn(v.y, rcp);
            xi[c4*4+1] = floorf(__builtin_fmaf(__builtin_fmaf(-s, q0, v.y), rcp, q0));
        }
        {
            const float q0 = __fmul_rn(v.z, rcp);
            xi[c4*4+2] = floorf(__builtin_fmaf(__builtin_fmaf(-s, q0, v.z), rcp, q0));
        }
        {
            const float q0 = __fmul_rn(v.w, rcp);
            xi[c4*4+3] = floorf(__builtin_fmaf(__builtin_fmaf(-s, q0, v.w), rcp, q0));
        }
    }

    // rowwise max (exact: integer-valued floats)
    float m = xi[0];
#pragma unroll
    for (int k = 1; k < 16; ++k) m = fmaxf(m, xi[k]);
#pragma unroll
    for (int off = 32; off >= 1; off >>= 1)
        m = fmaxf(m, __shfl_xor(m, off, 64));

    // table index: (int)(xi - m) + 2047 == (int)xi + base (both int-valued)
    const int base = (TSIZE - 1) - (int)m;
    int idx[16];
    int imin = TSIZE;
#pragma unroll
    for (int k = 0; k < 16; ++k) {
        idx[k] = (int)xi[k] + base;
        imin = min(imin, idx[k]);
    }

    float e[16];
    float psum = 0.0f;
    if (__builtin_expect(!__any(imin < 0), 1)) {
#pragma unroll
        for (int k = 0; k < 16; ++k) {
            e[k] = etab[idx[k]];
            psum += e[k];
        }
    } else {
        // exact fallback (wave-uniform, ~never taken): recompute from global
        float lo[16];
        float4 cf[16];
#pragma unroll
        for (int j = 0; j < 16; ++j) {
            lo[j] = lo_bounds[j];
            cf[j] = make_float4(coeffs[j*3+0], coeffs[j*3+1], coeffs[j*3+2], 0.0f);
        }
#pragma unroll
        for (int k = 0; k < 16; ++k) {
            e[k] = eval_e(xi[k] - m, lo, cf);
            psum += e[k];
        }
    }

    // rowwise sum (exact small-int f32, order-free)
    float sum = psum;
#pragma unroll
    for (int off = 32; off >= 1; off >>= 1)
        sum += __shfl_xor(sum, off, 64);

    const float factor = floorf(__fdiv_rn(4294967296.0f, fmaxf(sum, 1.0f)));
    const float factor25 = factor * (1.0f / 33554432.0f);  // exact pow2 scale

    // out = floor(RN(e*factor)*2^-25) * 2^-7  ==  floor(RN(e*factor25)) * 2^-7
    f32x4* const orow_v = (f32x4*)(out + row * (long long)ROW);
#pragma unroll
    for (int c4 = 0; c4 < 4; ++c4) {
        f32x4 o;
        o.x = floorf(__fmul_rn(e[c4*4+0], factor25)) * 0.0078125f;
        o.y = floorf(__fmul_rn(e[c4*4+1], factor25)) * 0.0078125f;
        o.z = floorf(__fmul_rn(e[c4*4+2], factor25)) * 0.0078125f;
        o.w = floorf(__fmul_rn(e[c4*4+3], factor25)) * 0.0078125f;
        __builtin_nontemporal_store(o, orow_v + c4 * 64 + lane);
    }
}

extern "C" void kernel_launch(void* const* d_in, const int* in_sizes, int n_in,
                              void* d_out, int out_size, void* d_ws, size_t ws_size,
                              hipStream_t stream) {
    const float* x      = (const float*)d_in[0];
    const float* s      = (const float*)d_in[1];
    const float* lo     = (const float*)d_in[2];
    // d_in[3] = hi_bounds (unused: segments contiguous, lo alone decides)
    const float* coeffs = (const float*)d_in[4];
    float* out = (float*)d_out;

    const int n = in_sizes[0];
    const int rows = n / ROW;
    const int blocks = (rows + WPB - 1) / WPB;

    if (ws_size >= TSIZE * sizeof(float)) {
        float* gtab = (float*)d_ws;
        hipLaunchKernelGGL(build_etab_kernel, dim3(TSIZE / 256), dim3(256), 0,
                           stream, lo, coeffs, gtab);
        hipLaunchKernelGGL(intsoftmax_kernel<true>, dim3(blocks), dim3(256), 0,
                           stream, x, s, lo, coeffs, gtab, out, rows);
    } else {
        hipLaunchKernelGGL(intsoftmax_kernel<false>, dim3(blocks), dim3(256), 0,
                           stream, x, s, lo, coeffs, (const float*)nullptr, out, rows);
    }
}